// Round 3
// baseline (136840.259 us; speedup 1.0000x reference)
//
#include <hip/hip_runtime.h>
#include <math.h>

typedef unsigned int u32;

#define T_SEQ   2048
#define BATCH   32
#define DHID    512

// ---------------- new workspace layout (bytes) ----------------
#define OFF_HBUF   0            // float[2][32][512] = 131072
#define OFF_FLAGS  131072       // u32[128] (1KB reserved)
#define OFF_LASTH  132096       // float[32][512] = 65536
#define OFF_XP     200704       // float[T][B][2048] = 536870912
#define WS_NEED    (200704ull + 536870912ull)

// ---------------- fallback (round-2 proven) layout ----------------
#define FB_OFF_HBUF   0
#define FB_OFF_ARRIVE 131072
#define FB_OFF_LASTH  131328

__device__ __forceinline__ float sigm(float x) { return 1.0f / (1.0f + expf(-x)); }

// =====================================================================
// Kernel 1: x_proj GEMM.  xp[t][b][g] = emb[x[b][t]] . Wih[g] + bih[g]+bhh[g]
// M = T*B (m = t*32+b), N = 2048, K = 512. Tile 64M x 128N, K-chunk 64.
// =====================================================================
__global__ void __launch_bounds__(256)
xp_gemm(const int* __restrict__ x, const float* __restrict__ emb,
        const float* __restrict__ Wih, const float* __restrict__ bih,
        const float* __restrict__ bhh, float* __restrict__ xp)
{
  __shared__ __align__(16) float At[64][64];    // chunk q stored at slot q^(m&7)
  __shared__ __align__(16) float Bt[128][64];   // chunk q stored at slot q^((n>>3)&7)
  __shared__ int xr[64];

  const int tid = threadIdx.x;
  const int mt = blockIdx.x, nt = blockIdx.y;

  if (tid < 64) {
    int m = mt * 64 + tid;
    xr[tid] = x[(m & 31) * 2048 + (m >> 5)];    // x[b][t], b=m&31, t=m>>5
  }
  const int mg = tid >> 4, ng = tid & 15;
  const int n0 = nt * 128 + ng * 8;
  float bb[8];
#pragma unroll
  for (int j = 0; j < 8; ++j) bb[j] = bih[n0 + j] + bhh[n0 + j];

  float acc[4][8];
#pragma unroll
  for (int i = 0; i < 4; ++i)
#pragma unroll
    for (int j = 0; j < 8; ++j) acc[i][j] = 0.f;

  __syncthreads();

  for (int ch = 0; ch < 8; ++ch) {
    const int k0 = ch * 64;
    { // stage A: 64 rows x 64 k
      int ml = tid >> 2, kp = (tid & 3) * 16;
      const float* src = emb + (size_t)xr[ml] * 512 + k0 + kp;
      int qb = kp >> 2, key = ml & 7;
#pragma unroll
      for (int j = 0; j < 4; ++j) {
        float4 v = *(const float4*)(src + 4 * j);
        *(float4*)&At[ml][(((qb + j) ^ key) << 2)] = v;
      }
    }
    { // stage B: 128 rows x 64 k
      int nl = tid >> 1, kp = (tid & 1) * 32;
      const float* src = Wih + (size_t)(nt * 128 + nl) * 512 + k0 + kp;
      int qb = kp >> 2, key = (nl >> 3) & 7;
#pragma unroll
      for (int j = 0; j < 8; ++j) {
        float4 v = *(const float4*)(src + 4 * j);
        *(float4*)&Bt[nl][(((qb + j) ^ key) << 2)] = v;
      }
    }
    __syncthreads();
#pragma unroll 4
    for (int kq = 0; kq < 16; ++kq) {
      float4 av[4], bv[8];
#pragma unroll
      for (int i = 0; i < 4; ++i) {
        int m = mg * 4 + i;
        av[i] = *(const float4*)&At[m][((kq ^ (m & 7)) << 2)];
      }
#pragma unroll
      for (int j = 0; j < 8; ++j) {
        int n = ng * 8 + j;
        bv[j] = *(const float4*)&Bt[n][((kq ^ ((n >> 3) & 7)) << 2)];
      }
#pragma unroll
      for (int i = 0; i < 4; ++i)
#pragma unroll
        for (int j = 0; j < 8; ++j)
          acc[i][j] += av[i].x * bv[j].x + av[i].y * bv[j].y +
                       av[i].z * bv[j].z + av[i].w * bv[j].w;
    }
    __syncthreads();
  }
  const int mbase = mt * 64 + mg * 4;
#pragma unroll
  for (int i = 0; i < 4; ++i) {
    float* dst = xp + (size_t)(mbase + i) * 2048 + n0;
#pragma unroll
    for (int j = 0; j < 8; ++j) dst[j] = acc[i][j] + bb[j];
  }
}

// =====================================================================
// Kernel 2: sequential LSTM. 128 WGs x 256 threads, all co-resident.
// WG = (ug = wg>>1 owning units ug*8..+8 -> 32 gate rows, bg = wg&1 owning
// 16 batches). h exchange via LLC-coherent sc0/sc1 accesses; NO fences.
// =====================================================================
__global__ void __launch_bounds__(256)
lstm_step(const int* __restrict__ attn, const float* __restrict__ Whh,
          const float* __restrict__ xp, float* __restrict__ hbuf,
          u32* __restrict__ flags, float* __restrict__ lasth)
{
  extern __shared__ float lds[];
  float* Wl  = lds;                       // [32][512], chunk q at slot q^(row&7)
  float* Hl  = lds + 32 * 512;            // [16][512], chunk q at slot q^(brow>>1)
  float* gsc = lds + 32 * 512 + 16 * 512; // [32][16]

  const int tid  = threadIdx.x;
  const int wg   = blockIdx.x;
  const int ug   = wg >> 1, bg = wg & 1;
  const int lane = tid & 63, wv = tid >> 6;
  const int rl   = lane & 7;              // unit-in-group (compute)
  const int bl   = lane >> 3;             // 0..7
  const int row  = wv * 8 + rl;           // 0..31 (gate = wv)
  const int grow = wv * 512 + ug * 8 + rl;
  const int b0l  = bl * 2, b1l = b0l + 1;
  const int b0   = bg * 16 + b0l, b1 = b0 + 1;

  // ---- W_hh slice -> LDS (swizzled), one-time ----
  {
    int rr = tid >> 3;                    // 0..31
    int gg = rr >> 3, uu = rr & 7;
    const float* src = Whh + (size_t)(gg * 512 + ug * 8 + uu) * 512 + (tid & 7) * 64;
    int qb = (tid & 7) * 16, key = rr & 7;
#pragma unroll
    for (int j = 0; j < 16; ++j) {
      float4 v = *(const float4*)(src + 4 * j);
      *(float4*)&Wl[rr * 512 + (((qb + j) ^ key) << 2)] = v;
    }
  }
  // ---- lengths (scratch in gsc as [16][16]) ----
  {
    int pb = tid >> 4, pc = tid & 15;
    const int4* ap = (const int4*)(attn + (size_t)(bg * 16 + pb) * 2048 + pc * 128);
    int s = 0;
#pragma unroll
    for (int k = 0; k < 32; ++k) { int4 a = ap[k]; s += a.x + a.y + a.z + a.w; }
    gsc[pb * 16 + pc] = (float)s;
  }
  __syncthreads();
  int len_reg = 0; float c_reg = 0.f;
  if (tid < 128) {
    int brow = tid >> 3;
    int s = 0;
#pragma unroll
    for (int k = 0; k < 16; ++k) s += (int)gsc[brow * 16 + k];
    len_reg = s - 1;
    if (len_reg < 0) len_reg = T_SEQ - 1;
  }
  __syncthreads();

  const int hkey = bl;
  for (int t = 0; t < T_SEQ; ++t) {
    // 1. xp prefetch (plain cached loads; h-independent, hides under poll)
    float xpv0 = xp[((size_t)t * 32 + b0) * 2048 + grow];
    float xpv1 = xp[((size_t)t * 32 + b1) * 2048 + grow];

    // 2. barrier: all WGs must have posted h_{t-1}  (flag value = step+1)
    if (tid < 128) {
      const u32* fp = flags + tid;
      while (1) {
        u32 v;
        asm volatile("global_load_dword %0, %1, off sc0 sc1\n\ts_waitcnt vmcnt(0)"
                     : "=v"(v) : "v"(fp) : "memory");
        if ((int)v >= t) break;
        __builtin_amdgcn_s_sleep(1);
      }
    }
    __syncthreads();

    // 3. fetch h_{t-1} from LLC into Hl (sc0 sc1 loads; swizzled dest)
    {
      const float* hsrc = hbuf + (((t + 1) & 1) << 14) + (size_t)(bg * 16) * 512;
      int brow = tid >> 4;
      int cb   = (tid & 15) * 8;          // dest chunk base (16B chunks)
      int key  = brow >> 1;
      const float* srcbase = hsrc + brow * 512;
      float4 hv[8];
#pragma unroll
      for (int j = 0; j < 8; ++j) {
        const float* s4 = srcbase + (((cb + j) ^ key) << 2);
        asm volatile("global_load_dwordx4 %0, %1, off sc0 sc1"
                     : "=v"(hv[j]) : "v"(s4) : "memory");
      }
      asm volatile("s_waitcnt vmcnt(0)" ::: "memory");
      __builtin_amdgcn_sched_barrier(0);
#pragma unroll
      for (int j = 0; j < 8; ++j)
        *(float4*)&Hl[brow * 512 + ((cb + j) << 2)] = hv[j];
    }
    __syncthreads();

    // 4. gate dots: row x {b0,b1} over K=512
    float a00 = 0, a01 = 0, a02 = 0, a03 = 0;
    float a10 = 0, a11 = 0, a12 = 0, a13 = 0;
    const float* wbase  = Wl + row * 512;
    const float* h0base = Hl + b0l * 512;
    const float* h1base = Hl + b1l * 512;
    const int wkey = row & 7;
#pragma unroll 8
    for (int kc = 0; kc < 128; ++kc) {
      float4 w4  = *(const float4*)(wbase  + ((kc ^ wkey) << 2));
      float4 h04 = *(const float4*)(h0base + ((kc ^ hkey) << 2));
      float4 h14 = *(const float4*)(h1base + ((kc ^ hkey) << 2));
      a00 += w4.x * h04.x; a01 += w4.y * h04.y; a02 += w4.z * h04.z; a03 += w4.w * h04.w;
      a10 += w4.x * h14.x; a11 += w4.y * h14.y; a12 += w4.z * h14.z; a13 += w4.w * h14.w;
    }
    gsc[row * 16 + b0l] = ((a00 + a01) + (a02 + a03)) + xpv0;
    gsc[row * 16 + b1l] = ((a10 + a11) + (a12 + a13)) + xpv1;
    __syncthreads();

    // 5. activations + coherent h store
    if (tid < 128) {
      int uu = tid & 7, brow = tid >> 3;
      float gi = gsc[(0 * 8 + uu) * 16 + brow];
      float gf = gsc[(1 * 8 + uu) * 16 + brow];
      float gg = gsc[(2 * 8 + uu) * 16 + brow];
      float go = gsc[(3 * 8 + uu) * 16 + brow];
      float iv = sigm(gi), fv = sigm(gf), ov = sigm(go), gv = tanhf(gg);
      c_reg = fv * c_reg + iv * gv;
      float hval = ov * tanhf(c_reg);
      int b = bg * 16 + brow, unit = ug * 8 + uu;
      float* dst = hbuf + ((t & 1) << 14) + b * 512 + unit;
      asm volatile("global_store_dword %0, %1, off sc0 sc1"
                   :: "v"(dst), "v"(hval) : "memory");
      if (t == len_reg) lasth[b * 512 + unit] = hval;
    }
    asm volatile("s_waitcnt vmcnt(0)" ::: "memory");   // h stores reached LLC
    __syncthreads();
    if (tid == 0) {
      u32 fv2 = (u32)(t + 1);
      u32* fdst = flags + wg;
      asm volatile("global_store_dword %0, %1, off sc0 sc1"
                   :: "v"(fdst), "v"(fv2) : "memory");
    }
  }
}

// =====================================================================
// FC head
// =====================================================================
__global__ void __launch_bounds__(128)
fc_kernel(const float* __restrict__ lasth, const float* __restrict__ fcW,
          const float* __restrict__ fcb, float* __restrict__ out)
{
  int tid = threadIdx.x;
  int b = tid >> 2, n = tid & 3;
  const float4* h4 = (const float4*)(lasth + (size_t)b * 512);
  const float4* w4 = (const float4*)(fcW + (size_t)n * 512);
  float s0 = 0.f, s1 = 0.f, s2 = 0.f, s3 = 0.f;
#pragma unroll 8
  for (int k = 0; k < 128; ++k) {
    float4 a = h4[k], c = w4[k];
    s0 += a.x * c.x; s1 += a.y * c.y; s2 += a.z * c.z; s3 += a.w * c.w;
  }
  out[b * 4 + n] = fcb[n] + ((s0 + s1) + (s2 + s3));
}

// =====================================================================
// Fallback: round-2 proven persistent kernel (used only if ws too small)
// =====================================================================
__device__ __forceinline__ void gl2lds16(const void* gsrc, void* ldst) {
  __builtin_amdgcn_global_load_lds(
      (const __attribute__((address_space(1))) u32*)gsrc,
      (__attribute__((address_space(3))) u32*)ldst, 16, 0, 0);
}

__global__ void __launch_bounds__(256)
lstm_persist(const int* __restrict__ xidx, const int* __restrict__ attn,
             const float* __restrict__ emb,
             const float* __restrict__ Wih, const float* __restrict__ Whh,
             const float* __restrict__ bih, const float* __restrict__ bhh,
             float* __restrict__ hbuf, float* __restrict__ lasth,
             u32* __restrict__ arrive)
{
  __shared__ __align__(16) float Wl[8][1024];
  __shared__ __align__(16) float ul[2][32][64];
  __shared__ float gsc[32][8];

  const int tid  = threadIdx.x;
  const int wg   = blockIdx.x;
  const int lane = tid & 63;
  const int wv   = tid >> 6;
  const int r    = tid & 7;
  const int bb   = tid >> 3;
  const int brl  = bb & 7;

#pragma unroll 2
  for (int i = 0; i < 8; ++i) {
    int ci = i * 256 + tid;
    int rr = ci >> 8;
    int cc = ci & 255;
    int R  = ((rr >> 1) << 9) + (wg * 2 + (rr & 1));
    const float* src = (cc < 128) ? (Wih + (size_t)R * 512 + cc * 4)
                                  : (Whh + (size_t)R * 512 + (cc - 128) * 4);
    float4 v = *(const float4*)src;
    int slot = cc ^ (rr & 7);
    *(float4*)&Wl[rr][slot * 4] = v;
  }
  float bias;
  {
    int R = ((r >> 1) << 9) + (wg * 2 + (r & 1));
    bias = bih[R] + bhh[R];
  }
  {
    int pb = tid >> 3, pc = tid & 7;
    const int4* ap = (const int4*)(attn + pb * 2048 + pc * 256);
    int s = 0;
#pragma unroll 8
    for (int k = 0; k < 64; ++k) { int4 a = ap[k]; s += a.x + a.y + a.z + a.w; }
    gsc[pb][pc] = (float)s;
  }
  __syncthreads();
  int   len_reg = 0;
  float c_reg   = 0.f;
  if (tid < 64) {
    int b2 = tid & 31;
    int s = 0;
#pragma unroll
    for (int k = 0; k < 8; ++k) s += (int)gsc[b2][k];
    len_reg = s - 1;
    if (len_reg < 0) len_reg = 2047;
  }
  __syncthreads();

  const int idx_b = 8 * wv + (lane & 7);
  int idx_cur = xidx[(size_t)idx_b * 2048];

  for (int t = 0; t < T_SEQ; ++t) {
    int idx_next = (t < T_SEQ - 1) ? xidx[(size_t)idx_b * 2048 + t + 1] : 0;
    float a0 = bias, a1 = 0.f, a2 = 0.f, a3 = 0.f;
    const float* hsrc = hbuf + (((t + 1) & 1) << 14);

    auto stageE = [&](int jt, int buf) {
#pragma unroll
      for (int q = 0; q < 2; ++q) {
        int rlq = 4 * q + (lane >> 4);
        int sc = lane & 15;
        int kc = sc ^ (rlq & 7);
        int rowg = __shfl(idx_cur, rlq, 64);
        const float* g = emb + (size_t)rowg * 512 + jt * 64 + kc * 4;
        gl2lds16(g, (void*)&ul[buf][8 * wv + 4 * q][0]);
      }
    };
    auto stageH = [&](int jt, int buf) {
#pragma unroll
      for (int q = 0; q < 2; ++q) {
        int rlq = 4 * q + (lane >> 4);
        int sc = lane & 15;
        int kc = sc ^ (rlq & 7);
        int blq = 8 * wv + rlq;
        const float* g = hsrc + (size_t)blq * 512 + jt * 64 + kc * 4;
        gl2lds16(g, (void*)&ul[buf][8 * wv + 4 * q][0]);
      }
    };
    auto computeT = [&](int jg, int buf) {
#pragma unroll
      for (int kc = 0; kc < 16; ++kc) {
        float4 uv4 = *(const float4*)&ul[buf][bb][(kc ^ brl) * 4];
        float4 wv4 = *(const float4*)&Wl[r][(((jg << 4) + kc) ^ r) * 4];
        a0 += uv4.x * wv4.x; a1 += uv4.y * wv4.y;
        a2 += uv4.z * wv4.z; a3 += uv4.w * wv4.w;
      }
    };

    stageE(0, 0);
#pragma unroll
    for (int jt = 0; jt < 8; ++jt) {
      if (jt < 7) { stageE(jt + 1, (jt + 1) & 1); asm volatile("s_waitcnt vmcnt(2)" ::: "memory"); }
      else       { asm volatile("s_waitcnt vmcnt(0)" ::: "memory"); }
      computeT(jt, jt & 1);
    }

    if (tid == 0) {
      u32 target = (u32)t << 8;
      while (__hip_atomic_load(arrive, __ATOMIC_RELAXED, __HIP_MEMORY_SCOPE_AGENT) < target)
        __builtin_amdgcn_s_sleep(2);
    }
    __syncthreads();
    __builtin_amdgcn_fence(__ATOMIC_ACQUIRE, "agent");

    stageH(0, 0);
#pragma unroll
    for (int jt = 0; jt < 8; ++jt) {
      if (jt < 7) { stageH(jt + 1, (jt + 1) & 1); asm volatile("s_waitcnt vmcnt(2)" ::: "memory"); }
      else       { asm volatile("s_waitcnt vmcnt(0)" ::: "memory"); }
      computeT(8 + jt, jt & 1);
    }

    gsc[bb][r] = a0 + a1 + a2 + a3;
    __syncthreads();
    if (tid < 64) {
      int u  = tid >> 5;
      int b2 = tid & 31;
      float gi = gsc[b2][u];
      float gf = gsc[b2][2 + u];
      float gg = gsc[b2][4 + u];
      float go = gsc[b2][6 + u];
      float iv = sigm(gi), fv = sigm(gf), ov = sigm(go);
      float gv = tanhf(gg);
      c_reg = fv * c_reg + iv * gv;
      float hv = ov * tanhf(c_reg);
      int unit = (wg << 1) + u;
      hbuf[((t & 1) << 14) + (b2 << 9) + unit] = hv;
      if (t == len_reg) lasth[(b2 << 9) + unit] = hv;
      __builtin_amdgcn_fence(__ATOMIC_RELEASE, "agent");
      if (tid == 0)
        __hip_atomic_fetch_add(arrive, 1u, __ATOMIC_RELAXED, __HIP_MEMORY_SCOPE_AGENT);
    }
    idx_cur = idx_next;
  }
}

extern "C" void kernel_launch(void* const* d_in, const int* in_sizes, int n_in,
                              void* d_out, int out_size, void* d_ws, size_t ws_size,
                              hipStream_t stream) {
  const int*   x    = (const int*)d_in[0];
  const int*   attn = (const int*)d_in[1];
  const float* emb  = (const float*)d_in[2];
  const float* Wih  = (const float*)d_in[3];
  const float* Whh  = (const float*)d_in[4];
  const float* bih  = (const float*)d_in[5];
  const float* bhh  = (const float*)d_in[6];
  const float* fcW  = (const float*)d_in[7];
  const float* fcb  = (const float*)d_in[8];
  float* out = (float*)d_out;
  char* ws = (char*)d_ws;

  if (ws_size >= WS_NEED) {
    float* hbuf   = (float*)(ws + OFF_HBUF);
    u32*   flags  = (u32*)(ws + OFF_FLAGS);
    float* lasth  = (float*)(ws + OFF_LASTH);
    float* xp     = (float*)(ws + OFF_XP);

    (void)hipMemsetAsync(ws, 0, 132096, stream);   // hbuf + flags

    hipLaunchKernelGGL(xp_gemm, dim3(1024, 16), dim3(256), 0, stream,
                       x, emb, Wih, bih, bhh, xp);

    (void)hipFuncSetAttribute((const void*)lstm_step,
                              hipFuncAttributeMaxDynamicSharedMemorySize, 100352);
    hipLaunchKernelGGL(lstm_step, dim3(128), dim3(256), 100352, stream,
                       attn, Whh, xp, hbuf, flags, lasth);

    hipLaunchKernelGGL(fc_kernel, dim3(1), dim3(128), 0, stream,
                       lasth, fcW, fcb, out);
  } else {
    // fallback: proven round-2 path
    float* hbuf   = (float*)(ws + FB_OFF_HBUF);
    u32*   arrive = (u32*)(ws + FB_OFF_ARRIVE);
    float* lasth  = (float*)(ws + FB_OFF_LASTH);
    (void)hipMemsetAsync(ws, 0, 131072 + 256, stream);
    hipLaunchKernelGGL(lstm_persist, dim3(256), dim3(256), 0, stream,
                       x, attn, emb, Wih, Whh, bih, bhh, hbuf, lasth, arrive);
    hipLaunchKernelGGL(fc_kernel, dim3(1), dim3(128), 0, stream,
                       lasth, fcW, fcb, out);
  }
}

// Round 6
// 34301.382 us; speedup vs baseline: 3.9894x; 3.9894x over previous
//
#include <hip/hip_runtime.h>
#include <math.h>

typedef unsigned int u32;

#define T_SEQ   2048
#define NWG     256

// ---------------- workspace layout (bytes) ----------------
#define OFF_HBUF   0            // float[2][32][512] = 131072
#define OFF_FLAGS  131072       // u32[256] = 1024
#define OFF_LASTH  132096       // float[32][512] = 65536
#define WS_NEED    197632ull

// ---------------- fallback (round-2 proven) layout ----------------
#define FB_OFF_HBUF   0
#define FB_OFF_ARRIVE 131072
#define FB_OFF_LASTH  131328

__device__ __forceinline__ float sigm(float x) { return 1.0f / (1.0f + expf(-x)); }

// ---- LLC-coherent data accessors (sc0 sc1 = bypass L1 + XCD L2) ----
// hbuf lines are ONLY ever touched via sc0sc1 ops -> never dirty in any L2.
__device__ __forceinline__ float4 ldg4s(const float* p) {
  float4 v;
  asm volatile("global_load_dwordx4 %0, %1, off sc0 sc1" : "=v"(v) : "v"(p) : "memory");
  return v;
}
__device__ __forceinline__ void stg1fs(float* p, float v) {
  asm volatile("global_store_dword %0, %1, off sc0 sc1" :: "v"(p), "v"(v) : "memory");
}

// =====================================================================
// Sequential LSTM: 256 WGs x 256 threads, plain launch (co-residency of
// 256 WGs at 1 WG/CU proven on this HW by rounds 2/3).
// bg = bid&7 (4 batches), slot = bid>>3 (16 units -> 64 gate rows).
// Thread (kg = tid>>4, rg = tid&15): 4 gate rows (rr = rg*4+i), k-slice
// [kg*32, kg*32+32). W entirely in VGPRs; k-partials reduced via LDS.
// Sync: per-group (32 WG) flags. Flags = compiler agent-scope atomics
// (proven coherent in r2/3). h data = sc0sc1 stores drained by vmcnt(0)
// BEFORE the flag post; consumers poll flag then sc0sc1-load h. No fences.
// Watchdog: poll caps ~0.5M iters -> sticky dead -> free-run (no hang).
// =====================================================================
__global__ void __launch_bounds__(256, 1)
lstm_seq(const int* __restrict__ x, const int* __restrict__ attn,
         const float* __restrict__ emb,
         const float* __restrict__ Wih, const float* __restrict__ Whh,
         const float* __restrict__ bih, const float* __restrict__ bhh,
         float* __restrict__ hbuf, u32* __restrict__ flags,
         float* __restrict__ lasth)
{
  __shared__ __align__(16) float red[16 * 260];
  __shared__ float gsc[256];
  __shared__ int s_dead;

  const int tid = threadIdx.x, bid = blockIdx.x;
  const int bg = bid & 7, slot = bid >> 3;
  const int kg = tid >> 4, rg = tid & 15;
  const int wv = tid >> 6, lane = tid & 63;

  // ---- W -> registers (64 float4 = 256 VGPR) ----
  float4 wE[4][8], wH[4][8];
#pragma unroll
  for (int i = 0; i < 4; ++i) {
    int rr = rg * 4 + i, g = rr >> 4, uu = rr & 15;
    const float* pE = Wih + (size_t)(g * 512 + slot * 16 + uu) * 512 + kg * 32;
    const float* pH = Whh + (size_t)(g * 512 + slot * 16 + uu) * 512 + kg * 32;
#pragma unroll
    for (int q = 0; q < 8; ++q) {
      wE[i][q] = *(const float4*)(pE + 4 * q);
      wH[i][q] = *(const float4*)(pH + 4 * q);
    }
  }

  // ---- lengths (partials in gsc) ----
  {
    int b = tid & 3, c = tid >> 2;   // c in [0,64)
    const int4* ap = (const int4*)(attn + (size_t)(bg * 4 + b) * 2048 + c * 32);
    int s = 0;
#pragma unroll
    for (int k = 0; k < 8; ++k) { int4 a = ap[k]; s += a.x + a.y + a.z + a.w; }
    gsc[c * 4 + b] = (float)s;
  }
  if (tid == 0) s_dead = 0;
  __syncthreads();
  int len = 0; float c_reg = 0.f;
  float bI = 0, bF = 0, bG = 0, bO = 0;
  if (tid < 64) {
    int b = tid & 3, uu = tid >> 2;
    int s = 0;
#pragma unroll
    for (int c = 0; c < 64; ++c) s += (int)gsc[c * 4 + b];
    len = s - 1; if (len < 0) len = T_SEQ - 1;
    int gu = slot * 16 + uu;
    bI = bih[gu]        + bhh[gu];
    bF = bih[512 + gu]  + bhh[512 + gu];
    bG = bih[1024 + gu] + bhh[1024 + gu];
    bO = bih[1536 + gu] + bhh[1536 + gu];
  }
  __syncthreads();   // gsc reusable

  const u32* fp = flags + bg * 32 + (lane & 31);
  bool dead = false;

  for (int t = 0; t < T_SEQ; ++t) {
    float acc[4][4];
#pragma unroll
    for (int i = 0; i < 4; ++i) { acc[i][0] = 0.f; acc[i][1] = 0.f; acc[i][2] = 0.f; acc[i][3] = 0.f; }

    // ---- emb half (h-independent; overlaps producer tail) ----
#pragma unroll
    for (int j = 0; j < 4; ++j) {
      int xr = x[(size_t)(bg * 4 + j) * 2048 + t];
      const float* ep = emb + (size_t)xr * 512 + kg * 32;
      float4 e[8];
#pragma unroll
      for (int q = 0; q < 8; ++q) e[q] = *(const float4*)(ep + 4 * q);
#pragma unroll
      for (int q = 0; q < 8; ++q)
#pragma unroll
        for (int i = 0; i < 4; ++i) {
          acc[i][j] += wE[i][q].x * e[q].x; acc[i][j] += wE[i][q].y * e[q].y;
          acc[i][j] += wE[i][q].z * e[q].z; acc[i][j] += wE[i][q].w * e[q].w;
        }
    }

    // ---- barrier: the 32 WGs of this bg posted h_{t-1} (wave 0 polls) ----
    if (wv == 0 && !dead) {
      int it = 0;
      while (true) {
        u32 v = __hip_atomic_load(fp, __ATOMIC_RELAXED, __HIP_MEMORY_SCOPE_AGENT);
        if (__all((int)v >= t)) break;
        if (++it > (1 << 19)) { s_dead = 1; break; }   // watchdog: no hang
        __builtin_amdgcn_s_sleep(2);
      }
    }
    __syncthreads();
    if (s_dead) dead = true;

    // ---- h half: sc0sc1 LLC loads, vmcnt(0)-drained ----
    const float* hsrc = hbuf + (((t + 1) & 1) << 14) + kg * 32;
#pragma unroll
    for (int jp = 0; jp < 2; ++jp) {
      const float* p0 = hsrc + (size_t)(bg * 4 + 2 * jp) * 512;
      const float* p1 = hsrc + (size_t)(bg * 4 + 2 * jp + 1) * 512;
      float4 hv0[8], hv1[8];
#pragma unroll
      for (int q = 0; q < 8; ++q) hv0[q] = ldg4s(p0 + 4 * q);
#pragma unroll
      for (int q = 0; q < 8; ++q) hv1[q] = ldg4s(p1 + 4 * q);
      asm volatile("s_waitcnt vmcnt(0)" ::: "memory");
      __builtin_amdgcn_sched_barrier(0);
#pragma unroll
      for (int q = 0; q < 8; ++q)
#pragma unroll
        for (int i = 0; i < 4; ++i) {
          acc[i][2 * jp]     += wH[i][q].x * hv0[q].x; acc[i][2 * jp]     += wH[i][q].y * hv0[q].y;
          acc[i][2 * jp]     += wH[i][q].z * hv0[q].z; acc[i][2 * jp]     += wH[i][q].w * hv0[q].w;
          acc[i][2 * jp + 1] += wH[i][q].x * hv1[q].x; acc[i][2 * jp + 1] += wH[i][q].y * hv1[q].y;
          acc[i][2 * jp + 1] += wH[i][q].z * hv1[q].z; acc[i][2 * jp + 1] += wH[i][q].w * hv1[q].w;
        }
    }

    // ---- k-split reduction via LDS ----
#pragma unroll
    for (int i = 0; i < 4; ++i) {
      int rr = rg * 4 + i;
      *(float4*)&red[kg * 260 + rr * 4] = make_float4(acc[i][0], acc[i][1], acc[i][2], acc[i][3]);
    }
    __syncthreads();
    {
      float s = 0.f;
#pragma unroll
      for (int k2 = 0; k2 < 16; ++k2) s += red[k2 * 260 + tid];
      gsc[tid] = s;
    }
    __syncthreads();

    // ---- activations + sc0sc1 h post (wave 0), then flag via atomic ----
    if (tid < 64) {
      int b = tid & 3, uu = tid >> 2;
      float gi = gsc[0 * 64 + uu * 4 + b] + bI;
      float gf = gsc[1 * 64 + uu * 4 + b] + bF;
      float gg = gsc[2 * 64 + uu * 4 + b] + bG;
      float go = gsc[3 * 64 + uu * 4 + b] + bO;
      float iv = sigm(gi), fv = sigm(gf), ov = sigm(go), gv = tanhf(gg);
      c_reg = fv * c_reg + iv * gv;
      float hval = ov * tanhf(c_reg);
      int bglob = bg * 4 + b, unit = slot * 16 + uu;
      float* hd = hbuf + ((t & 1) << 14) + (bglob << 9) + unit;
      stg1fs(hd, hval);
      if (t == len) lasth[(bglob << 9) + unit] = hval;
    }
    asm volatile("s_waitcnt vmcnt(0)" ::: "memory");   // wave0's h stores at LLC
    if (tid == 0)
      __hip_atomic_store(flags + bg * 32 + slot, (u32)(t + 1),
                         __ATOMIC_RELAXED, __HIP_MEMORY_SCOPE_AGENT);
  }
}

// =====================================================================
// FC head
// =====================================================================
__global__ void __launch_bounds__(128)
fc_kernel(const float* __restrict__ lasth, const float* __restrict__ fcW,
          const float* __restrict__ fcb, float* __restrict__ out)
{
  int tid = threadIdx.x;
  int b = tid >> 2, n = tid & 3;
  const float4* h4 = (const float4*)(lasth + (size_t)b * 512);
  const float4* w4 = (const float4*)(fcW + (size_t)n * 512);
  float s0 = 0.f, s1 = 0.f, s2 = 0.f, s3 = 0.f;
#pragma unroll 8
  for (int k = 0; k < 128; ++k) {
    float4 a = h4[k], c = w4[k];
    s0 += a.x * c.x; s1 += a.y * c.y; s2 += a.z * c.z; s3 += a.w * c.w;
  }
  out[b * 4 + n] = fcb[n] + ((s0 + s1) + (s2 + s3));
}

// =====================================================================
// Fallback: round-2 proven persistent kernel (only if ws too small)
// =====================================================================
__device__ __forceinline__ void gl2lds16(const void* gsrc, void* ldst) {
  __builtin_amdgcn_global_load_lds(
      (const __attribute__((address_space(1))) u32*)gsrc,
      (__attribute__((address_space(3))) u32*)ldst, 16, 0, 0);
}

__global__ void __launch_bounds__(256)
lstm_persist(const int* __restrict__ xidx, const int* __restrict__ attn,
             const float* __restrict__ emb,
             const float* __restrict__ Wih, const float* __restrict__ Whh,
             const float* __restrict__ bih, const float* __restrict__ bhh,
             float* __restrict__ hbuf, float* __restrict__ lasth,
             u32* __restrict__ arrive)
{
  __shared__ __align__(16) float Wl[8][1024];
  __shared__ __align__(16) float ul[2][32][64];
  __shared__ float gsc[32][8];

  const int tid  = threadIdx.x;
  const int wg   = blockIdx.x;
  const int lane = tid & 63;
  const int wv   = tid >> 6;
  const int r    = tid & 7;
  const int bb   = tid >> 3;
  const int brl  = bb & 7;

#pragma unroll 2
  for (int i = 0; i < 8; ++i) {
    int ci = i * 256 + tid;
    int rr = ci >> 8;
    int cc = ci & 255;
    int R  = ((rr >> 1) << 9) + (wg * 2 + (rr & 1));
    const float* src = (cc < 128) ? (Wih + (size_t)R * 512 + cc * 4)
                                  : (Whh + (size_t)R * 512 + (cc - 128) * 4);
    float4 v = *(const float4*)src;
    int slot = cc ^ (rr & 7);
    *(float4*)&Wl[rr][slot * 4] = v;
  }
  float bias;
  {
    int R = ((r >> 1) << 9) + (wg * 2 + (r & 1));
    bias = bih[R] + bhh[R];
  }
  {
    int pb = tid >> 3, pc = tid & 7;
    const int4* ap = (const int4*)(attn + pb * 2048 + pc * 256);
    int s = 0;
#pragma unroll 8
    for (int k = 0; k < 64; ++k) { int4 a = ap[k]; s += a.x + a.y + a.z + a.w; }
    gsc[pb][pc] = (float)s;
  }
  __syncthreads();
  int   len_reg = 0;
  float c_reg   = 0.f;
  if (tid < 64) {
    int b2 = tid & 31;
    int s = 0;
#pragma unroll
    for (int k = 0; k < 8; ++k) s += (int)gsc[b2][k];
    len_reg = s - 1;
    if (len_reg < 0) len_reg = 2047;
  }
  __syncthreads();

  const int idx_b = 8 * wv + (lane & 7);
  int idx_cur = xidx[(size_t)idx_b * 2048];

  for (int t = 0; t < T_SEQ; ++t) {
    int idx_next = (t < T_SEQ - 1) ? xidx[(size_t)idx_b * 2048 + t + 1] : 0;
    float a0 = bias, a1 = 0.f, a2 = 0.f, a3 = 0.f;
    const float* hsrc = hbuf + (((t + 1) & 1) << 14);

    auto stageE = [&](int jt, int buf) {
#pragma unroll
      for (int q = 0; q < 2; ++q) {
        int rlq = 4 * q + (lane >> 4);
        int sc = lane & 15;
        int kc = sc ^ (rlq & 7);
        int rowg = __shfl(idx_cur, rlq, 64);
        const float* g = emb + (size_t)rowg * 512 + jt * 64 + kc * 4;
        gl2lds16(g, (void*)&ul[buf][8 * wv + 4 * q][0]);
      }
    };
    auto stageH = [&](int jt, int buf) {
#pragma unroll
      for (int q = 0; q < 2; ++q) {
        int rlq = 4 * q + (lane >> 4);
        int sc = lane & 15;
        int kc = sc ^ (rlq & 7);
        int blq = 8 * wv + rlq;
        const float* g = hsrc + (size_t)blq * 512 + jt * 64 + kc * 4;
        gl2lds16(g, (void*)&ul[buf][8 * wv + 4 * q][0]);
      }
    };
    auto computeT = [&](int jg, int buf) {
#pragma unroll
      for (int kc = 0; kc < 16; ++kc) {
        float4 uv4 = *(const float4*)&ul[buf][bb][(kc ^ brl) * 4];
        float4 wv4 = *(const float4*)&Wl[r][(((jg << 4) + kc) ^ r) * 4];
        a0 += uv4.x * wv4.x; a1 += uv4.y * wv4.y;
        a2 += uv4.z * wv4.z; a3 += uv4.w * wv4.w;
      }
    };

    stageE(0, 0);
#pragma unroll
    for (int jt = 0; jt < 8; ++jt) {
      if (jt < 7) { stageE(jt + 1, (jt + 1) & 1); asm volatile("s_waitcnt vmcnt(2)" ::: "memory"); }
      else       { asm volatile("s_waitcnt vmcnt(0)" ::: "memory"); }
      computeT(jt, jt & 1);
    }

    if (tid == 0) {
      u32 target = (u32)t << 8;
      while (__hip_atomic_load(arrive, __ATOMIC_RELAXED, __HIP_MEMORY_SCOPE_AGENT) < target)
        __builtin_amdgcn_s_sleep(2);
    }
    __syncthreads();
    __builtin_amdgcn_fence(__ATOMIC_ACQUIRE, "agent");

    stageH(0, 0);
#pragma unroll
    for (int jt = 0; jt < 8; ++jt) {
      if (jt < 7) { stageH(jt + 1, (jt + 1) & 1); asm volatile("s_waitcnt vmcnt(2)" ::: "memory"); }
      else       { asm volatile("s_waitcnt vmcnt(0)" ::: "memory"); }
      computeT(8 + jt, jt & 1);
    }

    gsc[bb][r] = a0 + a1 + a2 + a3;
    __syncthreads();
    if (tid < 64) {
      int u  = tid >> 5;
      int b2 = tid & 31;
      float gi = gsc[b2][u];
      float gf = gsc[b2][2 + u];
      float gg = gsc[b2][4 + u];
      float go = gsc[b2][6 + u];
      float iv = sigm(gi), fv = sigm(gf), ov = sigm(go);
      float gv = tanhf(gg);
      c_reg = fv * c_reg + iv * gv;
      float hv = ov * tanhf(c_reg);
      int unit = (wg << 1) + u;
      hbuf[((t & 1) << 14) + (b2 << 9) + unit] = hv;
      if (t == len_reg) lasth[(b2 << 9) + unit] = hv;
      __builtin_amdgcn_fence(__ATOMIC_RELEASE, "agent");
      if (tid == 0)
        __hip_atomic_fetch_add(arrive, 1u, __ATOMIC_RELAXED, __HIP_MEMORY_SCOPE_AGENT);
    }
    idx_cur = idx_next;
  }
}

extern "C" void kernel_launch(void* const* d_in, const int* in_sizes, int n_in,
                              void* d_out, int out_size, void* d_ws, size_t ws_size,
                              hipStream_t stream) {
  const int*   x    = (const int*)d_in[0];
  const int*   attn = (const int*)d_in[1];
  const float* emb  = (const float*)d_in[2];
  const float* Wih  = (const float*)d_in[3];
  const float* Whh  = (const float*)d_in[4];
  const float* bih  = (const float*)d_in[5];
  const float* bhh  = (const float*)d_in[6];
  const float* fcW  = (const float*)d_in[7];
  const float* fcb  = (const float*)d_in[8];
  float* out = (float*)d_out;
  char* ws = (char*)d_ws;

  if (ws_size >= WS_NEED) {
    float* hbuf  = (float*)(ws + OFF_HBUF);
    u32*   flags = (u32*)(ws + OFF_FLAGS);
    float* lasth = (float*)(ws + OFF_LASTH);

    (void)hipMemsetAsync(ws, 0, 132096, stream);   // hbuf + flags

    hipLaunchKernelGGL(lstm_seq, dim3(NWG), dim3(256), 0, stream,
                       x, attn, emb, Wih, Whh, bih, bhh, hbuf, flags, lasth);
    hipLaunchKernelGGL(fc_kernel, dim3(1), dim3(128), 0, stream,
                       lasth, fcW, fcb, out);
  } else {
    float* hbuf   = (float*)(ws + FB_OFF_HBUF);
    u32*   arrive = (u32*)(ws + FB_OFF_ARRIVE);
    float* lasth  = (float*)(ws + FB_OFF_LASTH);
    (void)hipMemsetAsync(ws, 0, 131072 + 256, stream);
    hipLaunchKernelGGL(lstm_persist, dim3(256), dim3(256), 0, stream,
                       x, attn, emb, Wih, Whh, bih, bhh, hbuf, lasth, arrive);
    hipLaunchKernelGGL(fc_kernel, dim3(1), dim3(128), 0, stream,
                       lasth, fcW, fcb, out);
  }
}